// Round 1
// baseline (475.899 us; speedup 1.0000x reference)
//
#include <hip/hip_runtime.h>
#include <hip/hip_bf16.h>

// QuantizedConv2d: x[32,256,56,56] f32, q_weight[256,256,3,3] i32, w=q*s+m,
// conv 3x3 pad 1, + bias. Output f32 [32,256,56,56].
//
// v3:
//  - transpose_x: loop order fixed for L1 reuse (full 64B line per channel
//    consumed back-to-back into regs, then 16 packed stores). v2 was
//    L1-thrashing (~0.9 TB/s); this should be ~BW-bound.
//  - conv_mfma: T14 async-stage split. Global loads for the next stage are
//    issued right after the second barrier and land during the ~1600-cycle
//    MFMA phase; ds_writes at the next stage top consume the registers.

typedef __bf16 bf16x8 __attribute__((ext_vector_type(8)));
typedef float floatx4 __attribute__((ext_vector_type(4)));

#define XT_ELEMS 25690112L  // 32*256*56*56

// ---------------- kernel 1: dequantize weights ----------------
// w2 layout: [k9=kh*3+kw][o][i], bf16. One thread per (o,i) pair.
__global__ void dequant_w(const int* __restrict__ q, const float* __restrict__ sp,
                          const float* __restrict__ mp, __hip_bfloat16* __restrict__ w2) {
  int g = blockIdx.x * 256 + threadIdx.x;  // 0 .. 65535 = o*256+i
  float s = sp[0], m = mp[0];
  const int* qp = q + (long)g * 9;
#pragma unroll
  for (int j = 0; j < 9; j++) {
    float w = (float)qp[j] * s + m;
    w2[(long)j * 65536 + g] = __float2bfloat16(w);
  }
}

// ---------------- kernel 2: NCHW f32 -> NHWC bf16 ----------------
// Block: 64 px x 256 ch. Thread: 4 ch x 16 px.
// Loads: per channel, one full 64B line read as 4 consecutive float4 (L1 hit
// on 3/4). Stores: wave writes one contiguous 512B pixel row (64 x ushort4).
__global__ __launch_bounds__(256) void transpose_x(const float* __restrict__ x,
                                                   __hip_bfloat16* __restrict__ xt) {
  int n = blockIdx.y;
  int pb = blockIdx.x << 6;
  int t = threadIdx.x;
  int c0 = (t & 63) << 2;   // channel base, 4 channels per thread
  int p0 = (t >> 6) << 4;   // pixel base, 16 px per thread

  const float* src = x + (long)n * 802816 + pb + p0;
  __hip_bfloat16* dst = xt + ((long)(n * 3136 + pb + p0)) * 256 + c0;

  float v[4][16];
#pragma unroll
  for (int cj = 0; cj < 4; cj++) {
    const float* s = src + (long)(c0 + cj) * 3136;
#pragma unroll
    for (int pi = 0; pi < 4; pi++)
      *(float4*)&v[cj][pi * 4] = *(const float4*)(s + pi * 4);
  }
#pragma unroll
  for (int j = 0; j < 16; j++) {
    union {
      ushort4 u;
      __hip_bfloat16 h[4];
    } r;
#pragma unroll
    for (int cj = 0; cj < 4; cj++) r.h[cj] = __float2bfloat16(v[cj][j]);
    *(ushort4*)(dst + (long)j * 256) = r.u;
  }
}

// ---------------- kernel 3: direct conv via MFMA ----------------
// Block tile: 128 o x 224 px (4 rows x 56 cols, exact). 4 waves (2o x 2px),
// each wave 64 o x 112 px = 4x7 mfma 16x16x32 tiles.
// K loop: 8 channel blocks of 32 x 3 kh rows; per barrier pair we stage
// 3 taps of weights (and x tile when kh==0). Stage data is prefetched into
// registers during the PREVIOUS stage's MFMA phase (T14).
__global__ __launch_bounds__(256, 2) void conv_mfma(
    const __hip_bfloat16* __restrict__ xt, const __hip_bfloat16* __restrict__ w2,
    const float* __restrict__ bias, float* __restrict__ out) {
  __shared__ __align__(16) __hip_bfloat16 xs[6 * 58 * 40];     // 27840 B
  __shared__ __align__(16) __hip_bfloat16 wsh[3 * 128 * 40];   // 30720 B

  int ob = blockIdx.x;  // 0..1   o block
  int rb = blockIdx.y;  // 0..13  row block (4 rows each)
  int n = blockIdx.z;   // 0..31
  int t = threadIdx.x;
  int lane = t & 63;
  int wid = t >> 6;
  int wo = (wid & 1) << 6;     // wave o offset (0/64)
  int wpx = (wid >> 1) * 112;  // wave px offset (0/112)
  int l15 = lane & 15, quad = lane >> 4;
  int o0 = ob << 7;
  int h0 = rb << 2;

  // B-fragment LDS element bases, one per px tile
  int baddr[7];
#pragma unroll
  for (int tt = 0; tt < 7; tt++) {
    int px = wpx + tt * 16 + l15;  // 0..223
    int r = px / 56, c = px - r * 56;
    baddr[tt] = (r * 58 + c) * 40 + quad * 8;
  }

  // x staging precompute: 6*58 positions x 4 chunks of 16B = 1392 chunks
  int xlds[6];  // LDS element offset, -1 = inactive
  int xgo[6];   // global element offset (without i0), -1 = halo (stays zero)
#pragma unroll
  for (int it = 0; it < 6; it++) {
    int q = t + it * 256;
    xlds[it] = -1;
    xgo[it] = -1;
    if (q < 1392) {
      int pos = q >> 2, ck = q & 3;
      int row = pos / 58, col = pos - row * 58;
      int h = h0 - 1 + row, w = col - 1;
      bool v = (h >= 0) && (h < 56) && (w >= 0) && (w < 56);
      xlds[it] = pos * 40 + ck * 8;
      if (v) xgo[it] = (n * 3136 + h * 56 + w) * 256 + ck * 8;
    }
  }

  // weight staging precompute: 3*128 rows x 32 i = 1536 chunks
  int wlds[6], wbase[6];
#pragma unroll
  for (int it = 0; it < 6; it++) {
    int q2 = t + it * 256;  // 0..1535
    int tap = q2 >> 9;
    int rem = q2 & 511;
    int o_r = rem >> 2, ck = rem & 3;
    wlds[it] = (tap * 128 + o_r) * 40 + ck * 8;
    wbase[it] = (tap * 256 + o0 + o_r) * 256 + ck * 8;  // + kh*196608 + i0
  }

  // prologue prefetch for stage (ib=0, kh=0)
  int4 wreg[6], xreg[6];
#pragma unroll
  for (int it = 0; it < 6; it++)
    wreg[it] = *(const int4*)((const void*)(w2 + wbase[it]));
#pragma unroll
  for (int it = 0; it < 6; it++)
    if (xgo[it] >= 0) xreg[it] = *(const int4*)((const void*)(xt + xgo[it]));

  // zero halo cells once (never rewritten afterwards)
#pragma unroll
  for (int it = 0; it < 6; it++)
    if (xlds[it] >= 0 && xgo[it] < 0) *(int4*)((void*)(xs + xlds[it])) = (int4){0, 0, 0, 0};

  floatx4 acc[4][7];
#pragma unroll
  for (int m = 0; m < 4; m++)
#pragma unroll
    for (int tt = 0; tt < 7; tt++) acc[m][tt] = (floatx4){0.f, 0.f, 0.f, 0.f};

  for (int ib = 0; ib < 8; ib++) {
    for (int kh = 0; kh < 3; kh++) {
      __syncthreads();  // previous compute done before overwrite
      if (kh == 0) {
#pragma unroll
        for (int it = 0; it < 6; it++)
          if (xgo[it] >= 0) *(int4*)((void*)(xs + xlds[it])) = xreg[it];
      }
#pragma unroll
      for (int it = 0; it < 6; it++)
        *(int4*)((void*)(wsh + wlds[it])) = wreg[it];
      __syncthreads();

      // prefetch next stage; loads land during the MFMA phase below
      int nib = (kh == 2) ? ib + 1 : ib;
      int nkh = (kh == 2) ? 0 : kh + 1;
      if (nib < 8) {
        int noff = nkh * 196608 + nib * 32;
#pragma unroll
        for (int it = 0; it < 6; it++)
          wreg[it] = *(const int4*)((const void*)(w2 + wbase[it] + noff));
        if (nkh == 0) {
          int ni0 = nib * 32;
#pragma unroll
          for (int it = 0; it < 6; it++)
            if (xgo[it] >= 0) xreg[it] = *(const int4*)((const void*)(xt + xgo[it] + ni0));
        }
      }

#pragma unroll
      for (int kw = 0; kw < 3; kw++) {
        int koff = (kh * 58 + kw) * 40;
        bf16x8 a[4];
#pragma unroll
        for (int m = 0; m < 4; m++)
          a[m] = *(const bf16x8*)((const void*)(wsh + (kw * 128 + wo + m * 16 + l15) * 40 + quad * 8));
#pragma unroll
        for (int tt = 0; tt < 7; tt++) {
          bf16x8 b = *(const bf16x8*)((const void*)(xs + baddr[tt] + koff));
#pragma unroll
          for (int m = 0; m < 4; m++)
            acc[m][tt] = __builtin_amdgcn_mfma_f32_16x16x32_bf16(a[m], b, acc[m][tt], 0, 0, 0);
        }
      }
    }
  }

  // epilogue: C/D layout col=lane&15 (px), row=quad*4+reg (o)
#pragma unroll
  for (int m = 0; m < 4; m++) {
    int obase = o0 + wo + m * 16 + quad * 4;
#pragma unroll
    for (int r = 0; r < 4; r++) {
      int o = obase + r;
      float bv = bias[o];
      int outb = (n * 256 + o) * 3136 + h0 * 56;
#pragma unroll
      for (int tt = 0; tt < 7; tt++) {
        int px = wpx + tt * 16 + l15;
        out[outb + px] = acc[m][tt][r] + bv;
      }
    }
  }
}

extern "C" void kernel_launch(void* const* d_in, const int* in_sizes, int n_in,
                              void* d_out, int out_size, void* d_ws, size_t ws_size,
                              hipStream_t stream) {
  const float* x = (const float*)d_in[0];
  const int* qw = (const int*)d_in[1];
  const float* wscale = (const float*)d_in[2];
  const float* wmin = (const float*)d_in[3];
  const float* bias = (const float*)d_in[4];
  float* out = (float*)d_out;

  __hip_bfloat16* xt = (__hip_bfloat16*)d_ws;                          // 51,380,224 B
  __hip_bfloat16* w2 = (__hip_bfloat16*)((char*)d_ws + XT_ELEMS * 2);  // 1,179,648 B

  dequant_w<<<256, 256, 0, stream>>>(qw, wscale, wmin, w2);
  transpose_x<<<dim3(49, 32), 256, 0, stream>>>(x, xt);
  conv_mfma<<<dim3(2, 14, 32), 256, 0, stream>>>(xt, w2, bias, out);
}

// Round 3
// 462.403 us; speedup vs baseline: 1.0292x; 1.0292x over previous
//
#include <hip/hip_runtime.h>
#include <hip/hip_bf16.h>

// QuantizedConv2d: x[32,256,56,56] f32, q_weight[256,256,3,3] i32, w=q*s+m,
// conv 3x3 pad 1, + bias. Output f32 [32,256,56,56].
//
// v4 (resubmit; round-2 bench was an infra failure, no signal):
//  - transpose_x: LDS tile transpose, 64ch x 64px per block. Loads are
//    lane-contiguous in NCHW (256B/16 lanes per ch row); stores are
//    lane-contiguous in NHWC (64B/4 lanes per px). v2/v3 scattered each
//    wave load across 64 cache lines (~0.9 TB/s).
//  - conv_mfma: v2 schedule, but stage loads are issued BEFORE the first
//    barrier (reg liveness = barrier wait only, NOT the MFMA phase --
//    the v3 cross-MFMA liveness spilled to scratch: WRITE_SIZE 100->550MB).

typedef __bf16 bf16x8 __attribute__((ext_vector_type(8)));
typedef float floatx4 __attribute__((ext_vector_type(4)));

#define XT_ELEMS 25690112L  // 32*256*56*56

// ---------------- kernel 1: dequantize weights ----------------
// w2 layout: [k9=kh*3+kw][o][i], bf16. One thread per (o,i) pair.
__global__ void dequant_w(const int* __restrict__ q, const float* __restrict__ sp,
                          const float* __restrict__ mp, __hip_bfloat16* __restrict__ w2) {
  int g = blockIdx.x * 256 + threadIdx.x;  // 0 .. 65535 = o*256+i
  float s = sp[0], m = mp[0];
  const int* qp = q + (long)g * 9;
#pragma unroll
  for (int j = 0; j < 9; j++) {
    float w = (float)qp[j] * s + m;
    w2[(long)j * 65536 + g] = __float2bfloat16(w);
  }
}

// ---------------- kernel 2: NCHW f32 -> NHWC bf16, LDS tile ----------------
// Block: 64 ch x 64 px. Load: thread (t&15)->px quad, (t>>4)->ch quad;
// 16 lanes x float4 = 256B contiguous per channel row. In-register 4x4
// transpose -> LDS px-major (stride 72 ush, staggered write order).
// Store: 4 lanes x int4 = 64B contiguous per px, 2 int4 per thread.
__global__ __launch_bounds__(256) void transpose_x(const float* __restrict__ x,
                                                   __hip_bfloat16* __restrict__ xt) {
  __shared__ __align__(16) ushort lds[64 * 72];  // 9216 B
  int n = blockIdx.z;
  int pb = blockIdx.x << 6;  // pixel base (0..3072, step 64; 49*64=3136 exact)
  int cb = blockIdx.y << 6;  // channel base
  int t = threadIdx.x;
  int px0 = (t & 15) << 2;
  int c0 = (t >> 4) << 2;

  const float* src = x + (long)n * 802816 + (long)(cb + c0) * 3136 + pb + px0;
  float v[4][4];
#pragma unroll
  for (int cj = 0; cj < 4; cj++)
    *(float4*)v[cj] = *(const float4*)(src + (long)cj * 3136);

#pragma unroll
  for (int j = 0; j < 4; j++) {
    int jj = (j + t) & 3;  // stagger row order across lanes: 8-way -> ~4-way
    union {
      ushort4 u;
      __hip_bfloat16 h[4];
    } r;
#pragma unroll
    for (int cj = 0; cj < 4; cj++) r.h[cj] = __float2bfloat16(v[cj][jj]);
    *(ushort4*)&lds[(px0 + jj) * 72 + c0] = r.u;
  }
  __syncthreads();

  int px = t >> 2;
  int c8 = (t & 3) << 3;  // 0,8,16,24
  __hip_bfloat16* dst = xt + ((long)(n * 3136 + pb + px)) * 256 + cb;
  *(int4*)((void*)(dst + c8)) = *(const int4*)((const void*)&lds[px * 72 + c8]);
  *(int4*)((void*)(dst + c8 + 32)) = *(const int4*)((const void*)&lds[px * 72 + c8 + 32]);
}

// ---------------- kernel 3: direct conv via MFMA ----------------
// Block tile: 128 o x 224 px (4 rows x 56 cols, exact). 4 waves (2o x 2px),
// each wave 64 o x 112 px = 4x7 mfma 16x16x32 tiles.
// K loop: 8 channel blocks of 32 x 3 kh rows; per barrier pair we stage
// 3 taps of weights (and x tile when kh==0). Stage loads issue BEFORE the
// first barrier; regs die at the ds_write (no cross-MFMA liveness).
__global__ __launch_bounds__(256, 2) void conv_mfma(
    const __hip_bfloat16* __restrict__ xt, const __hip_bfloat16* __restrict__ w2,
    const float* __restrict__ bias, float* __restrict__ out) {
  __shared__ __align__(16) __hip_bfloat16 xs[6 * 58 * 40];    // 27840 B
  __shared__ __align__(16) __hip_bfloat16 wsh[3 * 128 * 40];  // 30720 B

  int ob = blockIdx.x;  // 0..1   o block
  int rb = blockIdx.y;  // 0..13  row block (4 rows each)
  int n = blockIdx.z;   // 0..31
  int t = threadIdx.x;
  int lane = t & 63;
  int wid = t >> 6;
  int wo = (wid & 1) << 6;     // wave o offset (0/64)
  int wpx = (wid >> 1) * 112;  // wave px offset (0/112)
  int l15 = lane & 15, quad = lane >> 4;
  int o0 = ob << 7;
  int h0 = rb << 2;

  // B-fragment LDS element bases, one per px tile
  int baddr[7];
#pragma unroll
  for (int tt = 0; tt < 7; tt++) {
    int px = wpx + tt * 16 + l15;  // 0..223
    int r = px / 56, c = px - r * 56;
    baddr[tt] = (r * 58 + c) * 40 + quad * 8;
  }

  // x staging precompute: 6*58 positions x 4 chunks of 16B = 1392 chunks
  int xlds[6];  // LDS element offset, -1 = inactive
  int xgo[6];   // global element offset (without i0), -1 = halo (stays zero)
#pragma unroll
  for (int it = 0; it < 6; it++) {
    int q = t + it * 256;
    xlds[it] = -1;
    xgo[it] = -1;
    if (q < 1392) {
      int pos = q >> 2, ck = q & 3;
      int row = pos / 58, col = pos - row * 58;
      int h = h0 - 1 + row, w = col - 1;
      bool v = (h >= 0) && (h < 56) && (w >= 0) && (w < 56);
      xlds[it] = pos * 40 + ck * 8;
      if (v) xgo[it] = (n * 3136 + h * 56 + w) * 256 + ck * 8;
    }
  }

  // weight staging precompute: 3*128 rows x 32 i = 1536 chunks
  int wlds[6], wbase[6];
#pragma unroll
  for (int it = 0; it < 6; it++) {
    int q2 = t + it * 256;  // 0..1535
    int tap = q2 >> 9;
    int rem = q2 & 511;
    int o_r = rem >> 2, ck = rem & 3;
    wlds[it] = (tap * 128 + o_r) * 40 + ck * 8;
    wbase[it] = (tap * 256 + o0 + o_r) * 256 + ck * 8;  // + kh*196608 + i0
  }

  // zero halo cells once (never rewritten afterwards)
#pragma unroll
  for (int it = 0; it < 6; it++)
    if (xlds[it] >= 0 && xgo[it] < 0) *(int4*)((void*)(xs + xlds[it])) = (int4){0, 0, 0, 0};

  floatx4 acc[4][7];
#pragma unroll
  for (int m = 0; m < 4; m++)
#pragma unroll
    for (int tt = 0; tt < 7; tt++) acc[m][tt] = (floatx4){0.f, 0.f, 0.f, 0.f};

  for (int ib = 0; ib < 8; ib++) {
    int i0 = ib * 32;
    for (int kh = 0; kh < 3; kh++) {
      // issue THIS stage's loads; latency overlaps the barrier wait below
      int4 wreg[6], xreg[6];
      int woff = kh * 196608 + i0;
#pragma unroll
      for (int it = 0; it < 6; it++)
        wreg[it] = *(const int4*)((const void*)(w2 + wbase[it] + woff));
      if (kh == 0) {
#pragma unroll
        for (int it = 0; it < 6; it++)
          if (xgo[it] >= 0) xreg[it] = *(const int4*)((const void*)(xt + xgo[it] + i0));
      }

      __syncthreads();  // previous compute done before overwrite
      if (kh == 0) {
#pragma unroll
        for (int it = 0; it < 6; it++)
          if (xgo[it] >= 0) *(int4*)((void*)(xs + xlds[it])) = xreg[it];
      }
#pragma unroll
      for (int it = 0; it < 6; it++)
        *(int4*)((void*)(wsh + wlds[it])) = wreg[it];
      __syncthreads();

#pragma unroll
      for (int kw = 0; kw < 3; kw++) {
        int koff = (kh * 58 + kw) * 40;
        bf16x8 a[4];
#pragma unroll
        for (int m = 0; m < 4; m++)
          a[m] = *(const bf16x8*)((const void*)(wsh + (kw * 128 + wo + m * 16 + l15) * 40 + quad * 8));
#pragma unroll
        for (int tt = 0; tt < 7; tt++) {
          bf16x8 b = *(const bf16x8*)((const void*)(xs + baddr[tt] + koff));
#pragma unroll
          for (int m = 0; m < 4; m++)
            acc[m][tt] = __builtin_amdgcn_mfma_f32_16x16x32_bf16(a[m], b, acc[m][tt], 0, 0, 0);
        }
      }
    }
  }

  // epilogue: C/D layout col=lane&15 (px), row=quad*4+reg (o)
#pragma unroll
  for (int m = 0; m < 4; m++) {
    int obase = o0 + wo + m * 16 + quad * 4;
#pragma unroll
    for (int r = 0; r < 4; r++) {
      int o = obase + r;
      float bv = bias[o];
      int outb = (n * 256 + o) * 3136 + h0 * 56;
#pragma unroll
      for (int tt = 0; tt < 7; tt++) {
        int px = wpx + tt * 16 + l15;
        out[outb + px] = acc[m][tt][r] + bv;
      }
    }
  }
}

extern "C" void kernel_launch(void* const* d_in, const int* in_sizes, int n_in,
                              void* d_out, int out_size, void* d_ws, size_t ws_size,
                              hipStream_t stream) {
  const float* x = (const float*)d_in[0];
  const int* qw = (const int*)d_in[1];
  const float* wscale = (const float*)d_in[2];
  const float* wmin = (const float*)d_in[3];
  const float* bias = (const float*)d_in[4];
  float* out = (float*)d_out;

  __hip_bfloat16* xt = (__hip_bfloat16*)d_ws;                          // 51,380,224 B
  __hip_bfloat16* w2 = (__hip_bfloat16*)((char*)d_ws + XT_ELEMS * 2);  // 1,179,648 B

  dequant_w<<<256, 256, 0, stream>>>(qw, wscale, wmin, w2);
  transpose_x<<<dim3(49, 4, 32), 256, 0, stream>>>(x, xt);
  conv_mfma<<<dim3(2, 14, 32), 256, 0, stream>>>(xt, w2, bias, out);
}

// Round 4
// 312.465 us; speedup vs baseline: 1.5230x; 1.4799x over previous
//
#include <hip/hip_runtime.h>
#include <hip/hip_bf16.h>

// QuantizedConv2d: x[32,256,56,56] f32, q_weight[256,256,3,3] i32, w=q*s+m,
// conv 3x3 pad 1, + bias. Output f32 [32,256,56,56].
//
// v5:
//  - conv_mfma: reverted to the v2 schedule (loads BETWEEN barriers --
//    v3/v4's pre-barrier issue demoted the staging regs to scratch:
//    WRITE_SIZE 100->583MB at unchanged VGPR=116). New: weight staging via
//    __builtin_amdgcn_global_load_lds width=16 (no VGPR round trip), with
//    the LDS bank-swizzle (c' = ck ^ ((rr>>1)&3)) baked into w2's GLOBAL
//    layout by dequant_w (rule 21: linear DMA dest + pre-swizzled source).
//    wsh shrinks 30.7->24.6KB -> 52.4KB total LDS -> 3 blocks/CU.
//  - transpose_x: v4 LDS-tile version kept (equal to v2 within noise).

typedef __bf16 bf16x8 __attribute__((ext_vector_type(8)));
typedef float floatx4 __attribute__((ext_vector_type(4)));

#define XT_ELEMS 25690112L  // 32*256*56*56

// global -> LDS direct DMA, 16B per lane. LDS dest = wave-uniform base +
// lane*16; global src is per-lane.
#define GLL16(g, l)                                             \
  __builtin_amdgcn_global_load_lds(                             \
      (const __attribute__((address_space(1))) void*)(g),       \
      (__attribute__((address_space(3))) void*)(l), 16, 0, 0)

// ---------------- kernel 1: dequantize weights ----------------
// w2 layout: 48 stages of 24576B, stage s = (ob*8+ib)*3+kh. Within a stage:
// chunk L = rr*4 + (ck ^ ((rr>>1)&3)), rr = kw*128 + o_r, each chunk 16B =
// 8 bf16 channels. Linear DMA into LDS then reproduces the swizzled layout.
__global__ void dequant_w(const int* __restrict__ q, const float* __restrict__ sp,
                          const float* __restrict__ mp, __hip_bfloat16* __restrict__ w2) {
  int g = blockIdx.x * 256 + threadIdx.x;  // 0 .. 65535 = o*256+i
  int o = g >> 8, i = g & 255;
  int ob = o >> 7, o_r = o & 127;
  int ib = i >> 5, ck = (i >> 3) & 3, e = i & 7;
  float s = sp[0], m = mp[0];
  const int* qp = q + (long)g * 9;
#pragma unroll
  for (int kh = 0; kh < 3; kh++) {
#pragma unroll
    for (int kw = 0; kw < 3; kw++) {
      float w = (float)qp[kh * 3 + kw] * s + m;
      int rr = kw * 128 + o_r;
      int cs = ck ^ ((rr >> 1) & 3);
      long dst = (long)((ob * 8 + ib) * 3 + kh) * 12288 + (rr * 4 + cs) * 8 + e;
      w2[dst] = __float2bfloat16(w);
    }
  }
}

// ---------------- kernel 2: NCHW f32 -> NHWC bf16, LDS tile ----------------
// Block: 64 ch x 64 px. Load: 16 lanes x float4 = 256B contiguous per ch row.
// Store: 4 lanes x int4 = 64B contiguous per px, 2 int4 per thread.
__global__ __launch_bounds__(256) void transpose_x(const float* __restrict__ x,
                                                   __hip_bfloat16* __restrict__ xt) {
  __shared__ __align__(16) ushort lds[64 * 72];  // 9216 B
  int n = blockIdx.z;
  int pb = blockIdx.x << 6;
  int cb = blockIdx.y << 6;
  int t = threadIdx.x;
  int px0 = (t & 15) << 2;
  int c0 = (t >> 4) << 2;

  const float* src = x + (long)n * 802816 + (long)(cb + c0) * 3136 + pb + px0;
  float v[4][4];
#pragma unroll
  for (int cj = 0; cj < 4; cj++)
    *(float4*)v[cj] = *(const float4*)(src + (long)cj * 3136);

#pragma unroll
  for (int j = 0; j < 4; j++) {
    int jj = (j + t) & 3;  // stagger write order across lanes
    union {
      ushort4 u;
      __hip_bfloat16 h[4];
    } r;
#pragma unroll
    for (int cj = 0; cj < 4; cj++) r.h[cj] = __float2bfloat16(v[cj][jj]);
    *(ushort4*)&lds[(px0 + jj) * 72 + c0] = r.u;
  }
  __syncthreads();

  int px = t >> 2;
  int c8 = (t & 3) << 3;
  __hip_bfloat16* dst = xt + ((long)(n * 3136 + pb + px)) * 256 + cb;
  *(int4*)((void*)(dst + c8)) = *(const int4*)((const void*)&lds[px * 72 + c8]);
  *(int4*)((void*)(dst + c8 + 32)) = *(const int4*)((const void*)&lds[px * 72 + c8 + 32]);
}

// ---------------- kernel 3: direct conv via MFMA ----------------
// Block tile: 128 o x 224 px (4 rows x 56 cols, exact). 4 waves (2o x 2px),
// each wave 64 o x 112 px = 4x7 mfma 16x16x32 tiles.
// K loop: 8 channel blocks of 32 x 3 kh rows; per barrier pair: weights DMA'd
// via global_load_lds (24 issues), x reg-staged on kh==0. v2 interleave.
__global__ __launch_bounds__(256, 2) void conv_mfma(
    const __hip_bfloat16* __restrict__ xt, const __hip_bfloat16* __restrict__ w2,
    const float* __restrict__ bias, float* __restrict__ out) {
  __shared__ __align__(16) __hip_bfloat16 xs[6 * 58 * 40];  // 27840 B
  __shared__ __align__(16) __hip_bfloat16 wsh[12288];       // 24576 B, linear

  int ob = blockIdx.x;  // 0..1   o block
  int rb = blockIdx.y;  // 0..13  row block (4 rows each)
  int n = blockIdx.z;   // 0..31
  int t = threadIdx.x;
  int lane = t & 63;
  int wid = t >> 6;
  int wo = (wid & 1) << 6;     // wave o offset (0/64)
  int wpx = (wid >> 1) * 112;  // wave px offset (0/112)
  int l15 = lane & 15, quad = lane >> 4;
  int o0 = ob << 7;
  int h0 = rb << 2;

  // A-fragment LDS base: row rr = kw*128 + wo + m*16 + l15, chunk quad ^ s.
  // s = (rr>>1)&3 reduces to (l15>>1)&3 (wo, m*16, kw*128 shift rr by
  // multiples of 16 -> (rr>>1)&3 invariant).
  int abase = (wo + l15) * 32 + ((quad ^ ((l15 >> 1) & 3))) * 8;

  // B-fragment LDS element bases, one per px tile
  int baddr[7];
#pragma unroll
  for (int tt = 0; tt < 7; tt++) {
    int px = wpx + tt * 16 + l15;  // 0..223
    int r = px / 56, c = px - r * 56;
    baddr[tt] = (r * 58 + c) * 40 + quad * 8;
  }

  // x staging precompute: 6*58 positions x 4 chunks of 16B = 1392 chunks
  int xlds[6];  // LDS element offset, -1 = inactive
  int xgo[6];   // global element offset (without i0), -1 = halo (stays zero)
#pragma unroll
  for (int it = 0; it < 6; it++) {
    int q = t + it * 256;
    xlds[it] = -1;
    xgo[it] = -1;
    if (q < 1392) {
      int pos = q >> 2, ck = q & 3;
      int row = pos / 58, col = pos - row * 58;
      int h = h0 - 1 + row, w = col - 1;
      bool v = (h >= 0) && (h < 56) && (w >= 0) && (w < 56);
      xlds[it] = pos * 40 + ck * 8;
      if (v) xgo[it] = (n * 3136 + h * 56 + w) * 256 + ck * 8;
    }
  }

  // zero halo cells once (never rewritten afterwards)
#pragma unroll
  for (int it = 0; it < 6; it++)
    if (xlds[it] >= 0 && xgo[it] < 0) *(int4*)((void*)(xs + xlds[it])) = (int4){0, 0, 0, 0};

  floatx4 acc[4][7];
#pragma unroll
  for (int m = 0; m < 4; m++)
#pragma unroll
    for (int tt = 0; tt < 7; tt++) acc[m][tt] = (floatx4){0.f, 0.f, 0.f, 0.f};

  const __hip_bfloat16* wsrc = w2 + (long)ob * (24 * 12288) + (long)wid * 3072 + lane * 8;

  for (int ib = 0; ib < 8; ib++) {
    int i0 = ib * 32;
    for (int kh = 0; kh < 3; kh++) {
      __syncthreads();  // previous compute done before overwrite
      // weights: 24 DMA issues (6 per wave), linear LDS, swizzle pre-baked
      {
        const __hip_bfloat16* src = wsrc + (long)(ib * 3 + kh) * 12288;
#pragma unroll
        for (int it = 0; it < 6; it++)
          GLL16(src + it * 512, wsh + wid * 3072 + it * 512);
      }
      if (kh == 0) {
#pragma unroll
        for (int it = 0; it < 6; it++)
          if (xgo[it] >= 0)
            *(int4*)((void*)(xs + xlds[it])) = *(const int4*)((const void*)(xt + xgo[it] + i0));
      }
      __syncthreads();  // drains vmcnt(0): DMA writes + ds_writes visible

#pragma unroll
      for (int kw = 0; kw < 3; kw++) {
        int koff = (kh * 58 + kw) * 40;
        bf16x8 a[4];
#pragma unroll
        for (int m = 0; m < 4; m++)
          a[m] = *(const bf16x8*)((const void*)(wsh + abase + kw * 4096 + m * 512));
#pragma unroll
        for (int tt = 0; tt < 7; tt++) {
          bf16x8 b = *(const bf16x8*)((const void*)(xs + baddr[tt] + koff));
#pragma unroll
          for (int m = 0; m < 4; m++)
            acc[m][tt] = __builtin_amdgcn_mfma_f32_16x16x32_bf16(a[m], b, acc[m][tt], 0, 0, 0);
        }
      }
    }
  }

  // epilogue: C/D layout col=lane&15 (px), row=quad*4+reg (o)
#pragma unroll
  for (int m = 0; m < 4; m++) {
    int obase = o0 + wo + m * 16 + quad * 4;
#pragma unroll
    for (int r = 0; r < 4; r++) {
      int o = obase + r;
      float bv = bias[o];
      int outb = (n * 256 + o) * 3136 + h0 * 56;
#pragma unroll
      for (int tt = 0; tt < 7; tt++) {
        int px = wpx + tt * 16 + l15;
        out[outb + px] = acc[m][tt][r] + bv;
      }
    }
  }
}

extern "C" void kernel_launch(void* const* d_in, const int* in_sizes, int n_in,
                              void* d_out, int out_size, void* d_ws, size_t ws_size,
                              hipStream_t stream) {
  const float* x = (const float*)d_in[0];
  const int* qw = (const int*)d_in[1];
  const float* wscale = (const float*)d_in[2];
  const float* wmin = (const float*)d_in[3];
  const float* bias = (const float*)d_in[4];
  float* out = (float*)d_out;

  __hip_bfloat16* xt = (__hip_bfloat16*)d_ws;                          // 51,380,224 B
  __hip_bfloat16* w2 = (__hip_bfloat16*)((char*)d_ws + XT_ELEMS * 2);  // 1,179,648 B

  dequant_w<<<256, 256, 0, stream>>>(qw, wscale, wmin, w2);
  transpose_x<<<dim3(49, 4, 32), 256, 0, stream>>>(x, xt);
  conv_mfma<<<dim3(2, 14, 32), 256, 0, stream>>>(xt, w2, bias, out);
}